// Round 5
// baseline (794.867 us; speedup 1.0000x reference)
//
#include <hip/hip_runtime.h>

#define SR 4
#define DD 9          // 2*SR+1
#define NIDX 81
#define HH 128
#define WW 128
#define CC 128
#define ROWS 4        // pixel rows per block
#define COLS 136      // WW + 2*SR (padded)
#define PPX 8         // pixels per lane-group
#define CHUNKC 32     // channels staged per phase
#define NCH (CC / CHUNKC)          // 4 chunk phases
#define C4S (CHUNKC / 4)           // 8 float4-blocks per cell
#define LDS_F4 (ROWS * COLS * C4S) // 4352 float4 = 69632 B (2 blocks/CU)

// scratch: [b][i_lin 0..8][h][w][j 0..8] floats
#define SCRATCH_FLOATS ((size_t)8 * 9 * HH * WW * DD)   // 10,616,832
#define SCRATCH_BYTES  (SCRATCH_FLOATS * 4)             // 42,467,328

template <bool DIRECT>
__global__ __launch_bounds__(256, 2)
void cost_volume_kernel(const float* __restrict__ x1,
                        const float* __restrict__ x2,
                        float* __restrict__ dst) {
    __shared__ float4 x2s4[LDS_F4];
    float* x2s = (float*)x2s4;

    const int tid  = threadIdx.x;
    const int wave = tid >> 6;        // 0..3  -> pixel row within strip
    const int lane = tid & 63;
    const int gl   = lane & 15;       // pixel group within row
    const int q    = lane >> 4;       // 4-way channel split

    const int b    = blockIdx.x >> 5;          // batch
    const int h0   = (blockIdx.x & 31) * ROWS; // strip base row
    const int half = blockIdx.y;               // i-range half

    const int row = wave;
    const int w0  = gl * PPX;

    const float* x1p = x1 + ((size_t)((b * HH + h0 + row) * WW + w0)) * CC;
    const float* x2b = x2 + (size_t)b * HH * WW * CC;

    const int c4w      = tid & (C4S - 1);   // staging: float4-block id (0..7)
    const int stage_hi = tid >> 3;          // staging: cell sub-id (0..31)

    const int i_lo = half ? 1 : -SR;
    const int i_hi = half ? SR : 0;

    for (int i = i_lo; i <= i_hi; ++i) {
        float acc[PPX][DD];
        #pragma unroll
        for (int p = 0; p < PPX; ++p)
            #pragma unroll
            for (int j = 0; j < DD; ++j) acc[p][j] = 0.f;

        for (int ch = 0; ch < NCH; ++ch) {
            const int cbase = ch * CHUNKC;
            __syncthreads();   // previous phase fully consumed before overwrite
            // ---- stage x2 rows (h0 + r - i), padded cols, channels [cbase, cbase+32) ----
            for (int k = 0; k < 17; ++k) {
                int tmp = stage_hi + (k << 5);      // 0..543 == r*136 + ps
                int r   = tmp / COLS;
                int ps  = tmp - r * COLS;
                int hp  = h0 + r - i;
                int wp  = ps - SR;
                float4 v = make_float4(0.f, 0.f, 0.f, 0.f);
                if ((unsigned)hp < (unsigned)HH && (unsigned)wp < (unsigned)WW)
                    v = *(const float4*)(x2b + (size_t)(hp * WW + wp) * CC + cbase + 4 * c4w);
                int slot4 = tmp * C4S + (c4w ^ ((ps >> 3) & 7));
                x2s4[slot4] = v;
            }
            __syncthreads();
            // ---- compute: 2 t-slices of 4 channels each ----
            #pragma unroll
            for (int t = 0; t < 2; ++t) {
                const int cl  = 16 * t + 4 * q;   // c_local within chunk
                const int c4v = 4 * t + q;        // float4-block index (0..7)

                float4 a[PPX];
                #pragma unroll
                for (int p = 0; p < PPX; ++p)
                    a[p] = *(const float4*)(x1p + p * CC + cbase + cl);

                float4 v[16];
                #pragma unroll
                for (int d = 0; d < 16; ++d) {
                    int ps    = w0 + d;
                    int slot4 = (row * COLS + ps) * C4S + (c4v ^ ((ps >> 3) & 7));
                    v[d] = x2s4[slot4];
                }

                #pragma unroll
                for (int p = 0; p < PPX; ++p) {
                    #pragma unroll
                    for (int j = 0; j < DD; ++j) {
                        const float4 xv = v[p + 8 - j];
                        float s = acc[p][j];
                        s = fmaf(a[p].x, xv.x, s);
                        s = fmaf(a[p].y, xv.y, s);
                        s = fmaf(a[p].z, xv.z, s);
                        s = fmaf(a[p].w, xv.w, s);
                        acc[p][j] = s;
                    }
                }
            }
        }

        // ---- reduce the 4-way c-split ----
        #pragma unroll
        for (int p = 0; p < PPX; ++p) {
            #pragma unroll
            for (int j = 0; j < DD; ++j) {
                float s = acc[p][j];
                s += __shfl_xor(s, 16, 64);
                s += __shfl_xor(s, 32, 64);
                acc[p][j] = s;
            }
        }

        const float inv = 1.0f / (float)HH;
        if (DIRECT) {
            // fallback: original scattered stores with idx wrap
            float* outp = dst + ((size_t)((b * HH + h0 + row) * WW)) * NIDX;
            #pragma unroll
            for (int p = 0; p < PPX; ++p) {
                if ((p >> 1) == q) {
                    float* op = outp + (size_t)(w0 + p) * NIDX;
                    #pragma unroll
                    for (int j = 0; j < DD; ++j) {
                        int idx = 9 * i + (j - SR);
                        if (idx < 0) idx += NIDX;
                        op[idx] = acc[p][j] * inv;
                    }
                }
            }
        } else {
            // dense scratch stores: [b][i+4][h][w][j] — contiguous per (i,row)
            const size_t rbase = (((size_t)(b * 9 + (i + 4)) * HH + (h0 + row)) * WW) * DD;
            #pragma unroll
            for (int p = 0; p < PPX; ++p) {
                if ((p >> 1) == q) {
                    float* sp = dst + rbase + (size_t)(w0 + p) * DD;
                    #pragma unroll
                    for (int j = 0; j < DD; ++j)
                        sp[j] = acc[p][j] * inv;
                }
            }
        }
    }
}

// scratch [b][i][h][w][j]  ->  out [b][h][w][c],  c = (9*i + j - 40) mod 81
__global__ __launch_bounds__(256)
void cv_transpose(const float* __restrict__ ws, float* __restrict__ out) {
    __shared__ float lds[32 * NIDX];   // 32 px * 81 ch = 10368 floats

    const int blk = blockIdx.x;
    const int wc  = blk & 3;            // 32-px chunk within row
    const int h   = (blk >> 2) & 127;
    const int b   = blk >> 9;

    const float* sb = ws + (size_t)b * 9 * HH * WW * DD + (size_t)h * WW * DD + wc * 32 * DD;

    // load 9 i-chunks of 288 contiguous floats; scatter into [w_local][c]
    for (int k = 0; k < 11; ++k) {
        int e = threadIdx.x + (k << 8);
        if (e < 9 * 288) {
            int il = e / 288;
            int r  = e - 288 * il;          // w_local*9 + j
            float v = sb[(size_t)il * (HH * WW * DD) + r];
            int j  = r % 9;
            int wl = r / 9;
            int n  = 9 * il + j - 40;
            if (n < 0) n += NIDX;
            lds[wl * NIDX + n] = v;
        }
    }
    __syncthreads();

    float* ob = out + ((size_t)(b * HH + h) * WW + wc * 32) * NIDX;
    for (int k = 0; k < 11; ++k) {
        int e = threadIdx.x + (k << 8);
        if (e < 32 * NIDX) ob[e] = lds[e];
    }
}

extern "C" void kernel_launch(void* const* d_in, const int* in_sizes, int n_in,
                              void* d_out, int out_size, void* d_ws, size_t ws_size,
                              hipStream_t stream) {
    const float* x1 = (const float*)d_in[0];
    const float* x2 = (const float*)d_in[1];
    float* out = (float*)d_out;
    (void)in_sizes; (void)n_in; (void)out_size;

    dim3 grid(256, 2);
    dim3 block(256);

    if (d_ws != nullptr && ws_size >= SCRATCH_BYTES) {
        float* scratch = (float*)d_ws;
        hipLaunchKernelGGL((cost_volume_kernel<false>), grid, block, 0, stream, x1, x2, scratch);
        hipLaunchKernelGGL(cv_transpose, dim3(4096), block, 0, stream, scratch, out);
    } else {
        hipLaunchKernelGGL((cost_volume_kernel<true>), grid, block, 0, stream, x1, x2, out);
    }
}

// Round 6
// 710.452 us; speedup vs baseline: 1.1188x; 1.1188x over previous
//
#include <hip/hip_runtime.h>
#include <stdint.h>

#define SR 4
#define DD 9          // 2*SR+1
#define NIDX 81
#define HH 128
#define WW 128
#define CC 128
#define ROWS 4        // rows per block; wave = row
#define CELLS 144     // padded window cols (valid ps: 0..135, ps = wp + SR)
#define CHUNKC 16     // channels per phase
#define C4S 4         // float4s per cell per chunk
#define ROW_F4 (CELLS * C4S)      // 576 f4 per row
#define BUF_F4 (ROWS * ROW_F4)    // 2304 f4 = 36864 B per buffer
#define ZBYTES 4096
#define SCR_OFF 4096
#define SCR_FLOATS ((size_t)8 * 9 * HH * WW * DD)   // [b][i+4][h][w][j]
#define SCR_BYTES (SCR_FLOATS * 4)

__device__ __forceinline__ void gload16(const void* g, void* l) {
    __builtin_amdgcn_global_load_lds(
        (const __attribute__((address_space(1))) void*)g,
        (__attribute__((address_space(3))) void*)l, 16, 0, 0);
}

// lane's 18-float contiguous run = pixels 2q, 2q+1 (9 floats each), 8B-aligned
#define ST18(A, B, g2)                         \
    do {                                       \
        g2[0] = make_float2(A[0], A[1]);       \
        g2[1] = make_float2(A[2], A[3]);       \
        g2[2] = make_float2(A[4], A[5]);       \
        g2[3] = make_float2(A[6], A[7]);       \
        g2[4] = make_float2(A[8], B[0]);       \
        g2[5] = make_float2(B[1], B[2]);       \
        g2[6] = make_float2(B[3], B[4]);       \
        g2[7] = make_float2(B[5], B[6]);       \
        g2[8] = make_float2(B[7], B[8]);       \
    } while (0)

template <bool SCRATCH>
__global__ __launch_bounds__(256, 2)
void cv_main(const float* __restrict__ x1, const float* __restrict__ x2,
             const float* __restrict__ zbuf, float* __restrict__ dst) {
    __shared__ float4 buf[2][BUF_F4];   // 73728 B total -> 2 blocks/CU

    const int tid  = threadIdx.x;
    const int wv   = tid >> 6;        // wave = window/compute row
    const int lane = tid & 63;
    const int gl   = lane & 15;       // 8-px group
    const int q    = lane >> 4;       // 4-way channel split
    const int w0   = gl * 8;

    const int b    = blockIdx.x >> 5;
    const int h0   = (blockIdx.x & 31) * ROWS;
    const int half = blockIdx.y;
    const int i_lo = half ? 1 : -SR;
    const int nph  = (half ? 4 : 5) * 8;   // (i-count) * 8 chunk phases

    const float* x1p = x1 + ((size_t)((b * HH + h0 + wv) * WW + w0)) * CC;
    const char*  x2c = (const char*)(x2 + (size_t)b * HH * WW * CC);

    float  acc[8][DD];
    float4 a0[8], a1[8];

    // ---- stage x2 row (h0+wv-i), chunk channels, into buf[tb] via global_load_lds.
    // LDS linear in lane; global source pre-swizzled:
    //   data(ps,c4) lives at f4-slot (ps^((ps>>3)&7))*4 + (c4^((ps>>3)&3))
    auto stage = [&](int ph, int tb) {
        const int i  = i_lo + (ph >> 3);
        const int cb = (ph & 7) * CHUNKC;
        const int hp = h0 + wv - i;
        const bool rowok = (unsigned)hp < (unsigned)HH;
        const char* rowg = x2c + (size_t)hp * (WW * CC * 4) + cb * 4;
        float4* drow = &buf[tb][wv * ROW_F4];
        #pragma unroll
        for (int k = 0; k < 9; ++k) {
            const int slot = 16 * k + (lane >> 2);   // slot-cell this lane fills
            const int sh   = 2 * k + (lane >> 5);    // == slot>>3
            const int ps   = slot ^ (sh & 7);        // inverse swizzle -> real cell
            const int c4   = (lane & 3) ^ (sh & 3);  // real c4
            const int wp   = ps - SR;
            const void* g = (rowok && (unsigned)wp < (unsigned)WW)
                          ? (const void*)(rowg + wp * 512 + c4 * 16)
                          : (const void*)((const char*)zbuf + ((64 * k + lane) & 255) * 16);
            gload16(g, (void*)(drow + 64 * k));      // uniform base + lane*16
        }
    };

    auto ldx1 = [&](int ph, float4* a) {
        const int cb = (ph & 7) * CHUNKC;
        #pragma unroll
        for (int p = 0; p < 8; ++p)
            a[p] = *(const float4*)(x1p + (size_t)p * CC + cb + 4 * q);
    };

    auto compute = [&](int tb, const float4* a) {
        const float4* src = &buf[tb][wv * ROW_F4];
        float4 v[16];
        #pragma unroll
        for (int d = 0; d < 16; ++d) {
            const int ps = w0 + d;
            const int sh = ps >> 3;
            v[d] = src[(ps ^ (sh & 7)) * 4 + (q ^ (sh & 3))];
        }
        #pragma unroll
        for (int p = 0; p < 8; ++p) {
            #pragma unroll
            for (int j = 0; j < DD; ++j) {
                const float4 xv = v[p + 8 - j];   // cell ps = w0+p+8-j  (wp = w0+p-(j-4))
                float s = acc[p][j];
                s = fmaf(a[p].x, xv.x, s);
                s = fmaf(a[p].y, xv.y, s);
                s = fmaf(a[p].z, xv.z, s);
                s = fmaf(a[p].w, xv.w, s);
                acc[p][j] = s;
            }
        }
    };

    auto flush = [&](int ph) {
        const int i = i_lo + (ph >> 3);
        #pragma unroll
        for (int p = 0; p < 8; ++p) {
            #pragma unroll
            for (int j = 0; j < DD; ++j) {
                float s = acc[p][j];
                s += __shfl_xor(s, 16, 64);
                s += __shfl_xor(s, 32, 64);
                acc[p][j] = s * (1.0f / (float)HH);
            }
        }
        if (SCRATCH) {
            const size_t rbase = (((size_t)(b * 9 + (i + 4)) * HH + (h0 + wv)) * WW) * DD;
            float2* g2 = (float2*)(dst + rbase + (size_t)w0 * DD + 18 * q);
            if      (q == 0) ST18(acc[0], acc[1], g2);
            else if (q == 1) ST18(acc[2], acc[3], g2);
            else if (q == 2) ST18(acc[4], acc[5], g2);
            else             ST18(acc[6], acc[7], g2);
        } else {
            float* outp = dst + ((size_t)((b * HH + h0 + wv) * WW)) * NIDX;
            #pragma unroll
            for (int p = 0; p < 8; ++p) {
                if ((p >> 1) == q) {
                    float* op = outp + (size_t)(w0 + p) * NIDX;
                    #pragma unroll
                    for (int j = 0; j < DD; ++j) {
                        int idx = 9 * i + (j - SR);
                        if (idx < 0) idx += NIDX;
                        op[idx] = acc[p][j];
                    }
                }
            }
        }
        #pragma unroll
        for (int p = 0; p < 8; ++p)
            #pragma unroll
            for (int j = 0; j < DD; ++j) acc[p][j] = 0.f;
    };

    #pragma unroll
    for (int p = 0; p < 8; ++p)
        #pragma unroll
        for (int j = 0; j < DD; ++j) acc[p][j] = 0.f;

    stage(0, 0);
    ldx1(0, a0);
    __syncthreads();                       // stage(0) landed

    for (int ph = 0; ph < nph; ph += 2) {
        // even phase: consume buf0/a0, prefetch into buf1/a1
        stage(ph + 1, 1);
        ldx1(ph + 1, a1);
        compute(0, a0);
        __syncthreads();                   // stage(ph+1) landed; buf0 free
        // odd phase: consume buf1/a1, prefetch into buf0/a0
        if (ph + 2 < nph) { stage(ph + 2, 0); ldx1(ph + 2, a0); }
        compute(1, a1);
        if (((ph + 1) & 7) == 7) flush(ph + 1);   // last chunk of this i
        __syncthreads();
    }
}

// scratch [b][il][h][w][j] -> out [b][h][w][c], c = (9*il + j - 40) mod 81
__global__ __launch_bounds__(288)
void cv_transpose(const float* __restrict__ ws, float* __restrict__ out) {
    __shared__ float lds[32 * NIDX];
    const int t   = threadIdx.x;            // 0..287 = wl*9 + j
    const int blk = blockIdx.x;
    const int wc  = blk & 3;
    const int h   = (blk >> 2) & 127;
    const int b   = blk >> 9;
    const int wl  = t / 9;
    const int j   = t - 9 * wl;

    const float* sb = ws + (size_t)b * 9 * (HH * WW * DD)
                         + (size_t)h * (WW * DD) + wc * (32 * DD) + t;
    #pragma unroll
    for (int il = 0; il < 9; ++il) {
        float v = sb[(size_t)il * (HH * WW * DD)];
        int n = 9 * il + j - 40;
        if (n < 0) n += NIDX;
        lds[wl * NIDX + n] = v;
    }
    __syncthreads();
    float* ob = out + ((size_t)(b * HH + h) * WW + wc * 32) * NIDX;
    #pragma unroll
    for (int k = 0; k < 9; ++k) ob[t + 288 * k] = lds[t + 288 * k];
}

// ---- legacy ultra-fallback (reg-staged, direct stores; no d_ws requirement) ----
#define LCOLS 136
#define LC4S 8
#define LLDS_F4 (ROWS * LCOLS * LC4S)
__global__ __launch_bounds__(256, 2)
void cv_legacy(const float* __restrict__ x1, const float* __restrict__ x2,
               float* __restrict__ out) {
    __shared__ float4 x2s4[LLDS_F4];
    const int tid = threadIdx.x, wave = tid >> 6, lane = tid & 63;
    const int gl = lane & 15, q = lane >> 4;
    const int b = blockIdx.x >> 5, h0 = (blockIdx.x & 31) * ROWS, half = blockIdx.y;
    const int row = wave, w0 = gl * 8;
    const float* x1p = x1 + ((size_t)((b * HH + h0 + row) * WW + w0)) * CC;
    const float* x2b = x2 + (size_t)b * HH * WW * CC;
    const int c4w = tid & 7, shi = tid >> 3;
    const int i_lo = half ? 1 : -SR, i_hi = half ? SR : 0;
    for (int i = i_lo; i <= i_hi; ++i) {
        float acc[8][DD];
        #pragma unroll
        for (int p = 0; p < 8; ++p)
            #pragma unroll
            for (int j = 0; j < DD; ++j) acc[p][j] = 0.f;
        for (int ch = 0; ch < 4; ++ch) {
            const int cbase = ch * 32;
            __syncthreads();
            for (int k = 0; k < 17; ++k) {
                int tmp = shi + (k << 5);
                int r = tmp / LCOLS, ps = tmp - r * LCOLS;
                int hp = h0 + r - i, wp = ps - SR;
                float4 v = make_float4(0.f, 0.f, 0.f, 0.f);
                if ((unsigned)hp < (unsigned)HH && (unsigned)wp < (unsigned)WW)
                    v = *(const float4*)(x2b + (size_t)(hp * WW + wp) * CC + cbase + 4 * c4w);
                x2s4[tmp * LC4S + (c4w ^ ((ps >> 3) & 7))] = v;
            }
            __syncthreads();
            #pragma unroll
            for (int t = 0; t < 2; ++t) {
                const int cl = 16 * t + 4 * q, c4v = 4 * t + q;
                float4 a[8];
                #pragma unroll
                for (int p = 0; p < 8; ++p)
                    a[p] = *(const float4*)(x1p + p * CC + cbase + cl);
                float4 v[16];
                #pragma unroll
                for (int d = 0; d < 16; ++d) {
                    int ps = w0 + d;
                    v[d] = x2s4[(row * LCOLS + ps) * LC4S + (c4v ^ ((ps >> 3) & 7))];
                }
                #pragma unroll
                for (int p = 0; p < 8; ++p)
                    #pragma unroll
                    for (int j = 0; j < DD; ++j) {
                        const float4 xv = v[p + 8 - j];
                        float s = acc[p][j];
                        s = fmaf(a[p].x, xv.x, s); s = fmaf(a[p].y, xv.y, s);
                        s = fmaf(a[p].z, xv.z, s); s = fmaf(a[p].w, xv.w, s);
                        acc[p][j] = s;
                    }
            }
        }
        #pragma unroll
        for (int p = 0; p < 8; ++p)
            #pragma unroll
            for (int j = 0; j < DD; ++j) {
                float s = acc[p][j];
                s += __shfl_xor(s, 16, 64);
                s += __shfl_xor(s, 32, 64);
                acc[p][j] = s;
            }
        const float inv = 1.0f / (float)HH;
        float* outp = out + ((size_t)((b * HH + h0 + row) * WW)) * NIDX;
        #pragma unroll
        for (int p = 0; p < 8; ++p)
            if ((p >> 1) == q) {
                float* op = outp + (size_t)(w0 + p) * NIDX;
                #pragma unroll
                for (int j = 0; j < DD; ++j) {
                    int idx = 9 * i + (j - SR);
                    if (idx < 0) idx += NIDX;
                    op[idx] = acc[p][j] * inv;
                }
            }
    }
}

extern "C" void kernel_launch(void* const* d_in, const int* in_sizes, int n_in,
                              void* d_out, int out_size, void* d_ws, size_t ws_size,
                              hipStream_t stream) {
    const float* x1 = (const float*)d_in[0];
    const float* x2 = (const float*)d_in[1];
    float* out = (float*)d_out;
    (void)in_sizes; (void)n_in; (void)out_size;

    dim3 block(256);
    dim3 grid(256, 2);   // (b, 4-row strip) x i-half = 512 blocks = 2/CU

    if (d_ws != nullptr && ws_size >= SCR_OFF + SCR_BYTES) {
        hipMemsetAsync(d_ws, 0, ZBYTES, stream);           // zero page for OOB lanes
        float* scr = (float*)((char*)d_ws + SCR_OFF);
        cv_main<true><<<grid, block, 0, stream>>>(x1, x2, (const float*)d_ws, scr);
        cv_transpose<<<dim3(4096), dim3(288), 0, stream>>>(scr, out);
    } else if (d_ws != nullptr && ws_size >= ZBYTES) {
        hipMemsetAsync(d_ws, 0, ZBYTES, stream);
        cv_main<false><<<grid, block, 0, stream>>>(x1, x2, (const float*)d_ws, out);
    } else {
        cv_legacy<<<grid, block, 0, stream>>>(x1, x2, out);
    }
}